// Round 2
// baseline (2799.180 us; speedup 1.0000x reference)
//
#include <hip/hip_runtime.h>

// CrossAttention on MI355X — round 2: spill-free LDS-staged matvecs.
//   k_qkv x3 : stage x-halo bf16 in LDS -> pointwise 96x96 matvec (8x8 reg
//              blocks, s_load weights) -> bf16 h in LDS -> depthwise 3x3 +
//              f32 residual (L2-hot re-read). q,k out bf16; v out f32.
//   k_gram   : gram partials (6 n-chunks, c-split 2) + fused q/k norm partials
//   k_attn   : reduce norms+gram, softmax, M[b] = proj @ attn_blockdiag
//   k_out    : out = M[b] @ v, v staged f32 in LDS (conflict-free b128 rows)

#define B_   8
#define C_   96
#define HH   192
#define WW   192
#define HW_  (HH*WW)      // 36864
#define HC_  32
#define TS   16           // output tile side
#define HS   18           // halo side
#define NHP  (HS*HS)      // 324 halo pixels
#define XP   104          // x_s row pad (bf16): 208B = 16*13 (odd) -> conflict-free b128
#define HP2  362          // h_s row pad (bf16): 724B = 181 banks (odd) -> conflict-free b32
#define VP   100          // v_s row pad (f32): 400B = 16*25 (odd) -> conflict-free b128

__device__ __forceinline__ unsigned short f2b(float f){
  unsigned u = __float_as_uint(f);
  u += 0x7fffu + ((u >> 16) & 1u);
  return (unsigned short)(u >> 16);
}
__device__ __forceinline__ float blo(unsigned u){ return __uint_as_float(u << 16); }
__device__ __forceinline__ float bhi(unsigned u){ return __uint_as_float(u & 0xffff0000u); }

__device__ __forceinline__ float dot8(uint4 a, uint4 b, float s){
  s = fmaf(blo(a.x), blo(b.x), s); s = fmaf(bhi(a.x), bhi(b.x), s);
  s = fmaf(blo(a.y), blo(b.y), s); s = fmaf(bhi(a.y), bhi(b.y), s);
  s = fmaf(blo(a.z), blo(b.z), s); s = fmaf(bhi(a.z), bhi(b.z), s);
  s = fmaf(blo(a.w), blo(b.w), s); s = fmaf(bhi(a.w), bhi(b.w), s);
  return s;
}

// ---------------- K1: fused pointwise + depthwise + residual ----------------
// grid (12,12,8), block 384 (6 waves). 1 block/CU (136.9 KB LDS).
template<int VOUT>  // 0: bf16 out (q,k), 1: f32 out (v)
__global__ __launch_bounds__(384, 1)
void k_qkv(const float* __restrict__ in, const float* __restrict__ pw,
           const float* __restrict__ dwt, void* __restrict__ outp)
{
  __shared__ unsigned short x_s[NHP * XP];   // 67,392 B  [pix][ch]
  __shared__ unsigned short h_s[C_ * HP2];   // 69,504 B  [ch][pix20]

  const int t  = threadIdx.x;
  const int b  = blockIdx.z;
  const int ty0 = blockIdx.y * TS, tx0 = blockIdx.x * TS;
  const float* xb = in + (size_t)b * C_ * HW_;

  // ---- phase 0: stage halo x (bf16) into x_s[pix][ch]
  #pragma unroll 1
  for (int r = 0; r < 81; ++r){           // 81*384 = 96*324
    const int idx = r * 384 + t;
    const int ch  = idx / NHP;
    const int pix = idx - ch * NHP;
    const int hy = pix / HS, hx = pix - hy * HS;
    const int gy = ty0 + hy - 1, gx = tx0 + hx - 1;
    float v = 0.f;
    if (gy >= 0 && gy < HH && gx >= 0 && gx < WW)
      v = xb[(size_t)ch * HW_ + gy * WW + gx];
    x_s[pix * XP + ch] = f2b(v);
  }
  __syncthreads();

  // ---- phase 1: h[c, pix] = pw @ x[:, pix]  (8-out x 8-in register blocks)
  if (t < NHP){
    const int p20 = (t / HS) * 20 + (t % HS);       // pitch-20 index in h_s
    const unsigned short* xrow = x_s + t * XP;
    #pragma unroll 1
    for (int c8 = 0; c8 < C_; c8 += 8){
      float acc[8] = {0.f,0.f,0.f,0.f,0.f,0.f,0.f,0.f};
      #pragma unroll
      for (int j8 = 0; j8 < 12; ++j8){
        const uint4 xv = *(const uint4*)(xrow + j8 * 8);
        float xf[8] = {blo(xv.x),bhi(xv.x),blo(xv.y),bhi(xv.y),
                       blo(xv.z),bhi(xv.z),blo(xv.w),bhi(xv.w)};
        #pragma unroll
        for (int jj = 0; jj < 8; ++jj){
          #pragma unroll
          for (int k = 0; k < 8; ++k)
            acc[k] = fmaf(pw[(c8 + k) * C_ + j8 * 8 + jj], xf[jj], acc[k]);
        }
      }
      #pragma unroll
      for (int k = 0; k < 8; ++k)
        h_s[(c8 + k) * HP2 + p20] = f2b(acc[k]);
    }
  }
  __syncthreads();

  // ---- phase 2: depthwise 3x3 + f32 residual; task = (tyy, c), c lane-minor
  const int c   = t % C_;
  const int ty4 = t / C_;                  // 0..3
  float w[9];
  #pragma unroll
  for (int i = 0; i < 9; ++i) w[i] = dwt[c * 9 + i];
  #pragma unroll 1
  for (int it = 0; it < 4; ++it){
    const int tyy = it * 4 + ty4;          // 0..15
    const int gy  = ty0 + tyy;
    float acc[TS];
    const float4* xr4 = (const float4*)(xb + (size_t)c * HW_ + (size_t)gy * WW + tx0);
    #pragma unroll
    for (int i = 0; i < 4; ++i){
      const float4 f = xr4[i];
      acc[4*i]=f.x; acc[4*i+1]=f.y; acc[4*i+2]=f.z; acc[4*i+3]=f.w;
    }
    #pragma unroll
    for (int dy = 0; dy < 3; ++dy){
      const unsigned* rp = (const unsigned*)(h_s + c * HP2 + (tyy + dy) * 20);
      float hv[HS];
      #pragma unroll
      for (int i = 0; i < 9; ++i){
        const unsigned u = rp[i];
        hv[2*i] = blo(u); hv[2*i+1] = bhi(u);
      }
      #pragma unroll
      for (int dx = 0; dx < 3; ++dx){
        const float wv = w[dy * 3 + dx];
        #pragma unroll
        for (int i = 0; i < TS; ++i) acc[i] = fmaf(wv, hv[i + dx], acc[i]);
      }
    }
    const size_t o = ((size_t)b * C_ + c) * HW_ + (size_t)gy * WW + tx0;
    if (VOUT){
      float4* op = (float4*)((float*)outp + o);
      #pragma unroll
      for (int i = 0; i < 4; ++i)
        op[i] = make_float4(acc[4*i], acc[4*i+1], acc[4*i+2], acc[4*i+3]);
    } else {
      uint4* op = (uint4*)((unsigned short*)outp + o);
      unsigned pk[8];
      #pragma unroll
      for (int i = 0; i < 8; ++i)
        pk[i] = (unsigned)f2b(acc[2*i]) | ((unsigned)f2b(acc[2*i+1]) << 16);
      op[0] = make_uint4(pk[0], pk[1], pk[2], pk[3]);
      op[1] = make_uint4(pk[4], pk[5], pk[6], pk[7]);
    }
  }
}

// ---------------- K2: gram partials + fused norm partials ----------------
// grid (2 c-split, 6 n-split, 24 bh), block 512 = 16c x 32d. No atomics.
__global__ __launch_bounds__(512)
void k_gram(const unsigned short* __restrict__ qb, const unsigned short* __restrict__ kb,
            float* __restrict__ Gp, float* __restrict__ qq_p, float* __restrict__ kk_p)
{
  const int t  = threadIdx.x;
  const int d  = t & 31, cl = t >> 5;          // cl 0..15
  const int c  = blockIdx.x * 16 + cl;
  const int ns = blockIdx.y;
  const int bh = blockIdx.z, b = bh / 3, h = bh - b * 3;
  const uint4* qr = (const uint4*)(qb + ((size_t)b * C_ + h * HC_ + c) * HW_) + ns * 768;
  const uint4* kr = (const uint4*)(kb + ((size_t)b * C_ + h * HC_ + d) * HW_) + ns * 768;
  float a0 = 0.f, a1 = 0.f;
  #pragma unroll 2
  for (int i = 0; i < 768; i += 2){
    a0 = dot8(qr[i],   kr[i],   a0);
    a1 = dot8(qr[i+1], kr[i+1], a1);
  }
  Gp[(((size_t)ns * 24 + bh) * HC_ + c) * HC_ + d] = a0 + a1;

  // qq partial for row c: thread d covers i in [d*24, d*24+24)  (L1-hot re-read)
  float s = 0.f;
  #pragma unroll 4
  for (int i = d * 24; i < d * 24 + 24; ++i) s = dot8(qr[i], qr[i], s);
  #pragma unroll
  for (int m = 16; m; m >>= 1) s += __shfl_xor(s, m);
  if (d == 0) qq_p[((size_t)ns * 24 + bh) * HC_ + c] = s;

  // kk partial for row d (only c-split 0): thread cl covers i in [cl*48, +48)
  if (blockIdx.x == 0){
    float s2 = 0.f;
    #pragma unroll 4
    for (int i = cl * 48; i < cl * 48 + 48; ++i) s2 = dot8(kr[i], kr[i], s2);
    __shared__ float red[16][32];
    red[cl][d] = s2;
    __syncthreads();
    if (t < 32){
      float r = 0.f;
      #pragma unroll
      for (int j = 0; j < 16; ++j) r += red[j][t];
      kk_p[((size_t)ns * 24 + bh) * HC_ + t] = r;
    }
  }
}

// ---------------- K3: norms + softmax + M = proj @ attn_bd ----------------
__global__ __launch_bounds__(256)
void k_attn(const float* __restrict__ Gp, const float* __restrict__ qq_p,
            const float* __restrict__ kk_p, const float* __restrict__ temp,
            const float* __restrict__ proj, float* __restrict__ M)
{
  const int b = blockIdx.x, t = threadIdx.x;
  __shared__ float at[3][HC_][HC_];
  __shared__ float ninv[2][C_];
  if (t < 2 * C_){
    const int kind = t / C_, r = t - kind * C_;
    const int bh = b * 3 + r / HC_, cc = r & 31;
    const float* P = kind ? kk_p : qq_p;
    float s = 0.f;
    #pragma unroll
    for (int ns = 0; ns < 6; ++ns) s += P[((size_t)ns * 24 + bh) * HC_ + cc];
    ninv[kind][r] = 1.f / fmaxf(sqrtf(s), 1e-12f);
  }
  __syncthreads();
  for (int idx = t; idx < 3 * HC_ * HC_; idx += 256){
    const int h = idx >> 10, rem = idx & 1023, cc = rem >> 5, dd = rem & 31;
    float g = 0.f;
    #pragma unroll
    for (int ns = 0; ns < 6; ++ns)
      g += Gp[(((size_t)ns * 24 + b * 3 + h) * HC_ + cc) * HC_ + dd];
    at[h][cc][dd] = g * ninv[0][h * HC_ + cc] * ninv[1][h * HC_ + dd] * temp[h];
  }
  __syncthreads();
  if (t < C_){
    const int h = t >> 5, cc = t & 31;
    float m = -1e30f;
    for (int dd = 0; dd < HC_; dd++) m = fmaxf(m, at[h][cc][dd]);
    float s = 0.f;
    for (int dd = 0; dd < HC_; dd++){ float e = expf(at[h][cc][dd] - m); at[h][cc][dd] = e; s += e; }
    const float inv = 1.f / s;
    for (int dd = 0; dd < HC_; dd++) at[h][cc][dd] *= inv;
  }
  __syncthreads();
  for (int idx = t; idx < C_ * C_; idx += 256){
    const int o = idx / 96, hd = idx - o * 96, h = hd >> 5, dd = hd & 31;
    float m = 0.f;
    #pragma unroll
    for (int cc = 0; cc < HC_; cc++)
      m = fmaf(proj[o * C_ + h * HC_ + cc], at[h][cc][dd], m);
    M[(size_t)b * C_ * C_ + idx] = m;
  }
}

// ---------------- K4: out = M[b] @ v (fused attn-apply + proj) ----------------
// grid (144,8), block 256. v staged f32 in LDS (conflict-free b128 rows).
__global__ __launch_bounds__(256, 1)
void k_out(const float* __restrict__ vf, const float* __restrict__ M,
           float* __restrict__ out)
{
  __shared__ float v_s[256 * VP];          // 102,400 B  [pix][ch]
  const int t  = threadIdx.x;
  const int b  = blockIdx.y;
  const int p0 = blockIdx.x * 256;
  const float* vb = vf + (size_t)b * C_ * HW_ + p0;
  #pragma unroll 1
  for (int ch = 0; ch < C_; ++ch)
    v_s[t * VP + ch] = vb[(size_t)ch * HW_ + t];
  __syncthreads();

  const float* Mb   = M + (size_t)b * C_ * C_;
  const float* vrow = v_s + t * VP;
  float* ob = out + (size_t)b * C_ * HW_ + p0 + t;
  #pragma unroll 1
  for (int o8 = 0; o8 < C_; o8 += 8){
    float acc[8] = {0.f,0.f,0.f,0.f,0.f,0.f,0.f,0.f};
    #pragma unroll
    for (int j4 = 0; j4 < 24; ++j4){
      const float4 v4 = *(const float4*)(vrow + j4 * 4);
      const float vv[4] = {v4.x, v4.y, v4.z, v4.w};
      #pragma unroll
      for (int jj = 0; jj < 4; ++jj){
        #pragma unroll
        for (int k = 0; k < 8; ++k)
          acc[k] = fmaf(Mb[(o8 + k) * C_ + j4 * 4 + jj], vv[jj], acc[k]);
      }
    }
    #pragma unroll
    for (int k = 0; k < 8; ++k)
      ob[(size_t)(o8 + k) * HW_] = acc[k];
  }
}

extern "C" void kernel_launch(void* const* d_in, const int* in_sizes, int n_in,
                              void* d_out, int out_size, void* d_ws, size_t ws_size,
                              hipStream_t stream)
{
  const float* x    = (const float*)d_in[0];
  const float* y    = (const float*)d_in[1];
  const float* z    = (const float*)d_in[2];
  const float* temp = (const float*)d_in[3];
  const float* q_pw = (const float*)d_in[4];
  const float* q_dw = (const float*)d_in[5];
  const float* k_pw = (const float*)d_in[6];
  const float* k_dw = (const float*)d_in[7];
  const float* v_pw = (const float*)d_in[8];
  const float* v_dw = (const float*)d_in[9];
  const float* proj = (const float*)d_in[10];

  // workspace layout (bytes); M aliases qb (dead after k_gram). total 227.1 MB
  char* ws = (char*)d_ws;
  unsigned short* qb = (unsigned short*)(ws);                  // 56,623,104
  unsigned short* kb = (unsigned short*)(ws + 56623104);       // 56,623,104
  float* vf  = (float*)(ws + 113246208);                       // 113,246,208
  float* Gp  = (float*)(ws + 226492416);                       // 589,824
  float* qqp = (float*)(ws + 227082240);                       // 18,432
  float* kkp = (float*)(ws + 227100672);                       // 18,432
  float* M   = (float*)(ws);                                   // aliases qb
  float* out = (float*)d_out;

  const dim3 g1(12, 12, B_);
  k_qkv<0><<<g1, 384, 0, stream>>>(x, q_pw, q_dw, qb);
  k_qkv<0><<<g1, 384, 0, stream>>>(y, k_pw, k_dw, kb);
  k_qkv<1><<<g1, 384, 0, stream>>>(z, v_pw, v_dw, vf);
  k_gram<<<dim3(2, 6, B_ * 3), 512, 0, stream>>>(qb, kb, Gp, qqp, kkp);
  k_attn<<<B_, 256, 0, stream>>>(Gp, qqp, kkp, temp, proj, M);
  k_out<<<dim3(HW_ / 256, B_), 256, 0, stream>>>(vf, M, out);
}

// Round 4
// 638.922 us; speedup vs baseline: 4.3811x; 4.3811x over previous
//
#include <hip/hip_runtime.h>

// CrossAttention MI355X — round 4 (= round-3 design, kernel renamed to fix
// host-symbol collision with d_in alias `k_dw`).
//  k_gemm<0,0,0> x3 : h = pw @ x          (bf16 out via LDS-transpose epilogue)
//  k_dwise<NORM> x3 : q/k/v = x + dw3x3(h), fused L2-norm partials (q,k)
//  k_gram           : G[b,h] = q @ k^T    (32x32x16 MFMA, straight-copy panels)
//  k_attn           : norms + softmax + M[b] = proj @ attn_blockdiag
//  k_gemm<1,1,1>    : out = M[b] @ v      (f32 direct epilogue)

#define B_  8
#define C_  96
#define W_  192
#define HW_ 36864

typedef __attribute__((ext_vector_type(8)))  short short8;
typedef __attribute__((ext_vector_type(4)))  float f32x4;
typedef __attribute__((ext_vector_type(16))) float f32x16;

__device__ __forceinline__ unsigned short f2b(float f){
  unsigned u = __float_as_uint(f);
  u += 0x7fffu + ((u >> 16) & 1u);
  return (unsigned short)(u >> 16);
}
__device__ __forceinline__ float blo(unsigned u){ return __uint_as_float(u << 16); }
__device__ __forceinline__ float bhi(unsigned u){ return __uint_as_float(u & 0xffff0000u); }

// ---------------- k_gemm: D[96][36864] = A(96x96) @ B(96x36864) per batch ----
// grid (144, 8), block 256 (4 waves). Wave w owns pixels [w*64, w*64+64).
// MFMA 16x16x32 bf16: A-frag m=lane&15 rows, k=(lane>>4)*8 contig; B staged
// transposed [pix][104ch] (208B rows: 16B-aligned, conflict-free b128).
template<int OUT_F32, int IN_BF16, int A_PER_B>
__global__ __launch_bounds__(256, 2)
void k_gemm(const void* __restrict__ Bsrc, const float* __restrict__ Asrc,
            void* __restrict__ Dst)
{
  __shared__ unsigned short xT[256 * 104];   // 53,248 B  [pix][ch]
  __shared__ unsigned short aw[96 * 104];    // 19,968 B  [m][k]
  const int t = threadIdx.x;
  const int b = blockIdx.y;
  const int p0 = blockIdx.x * 256;
  const int lane = t & 63, w = t >> 6;
  const int l15 = lane & 15, l4 = lane >> 4;

  // stage A: f32 -> bf16 pairs (4608 pair-writes)
  const float* Ab = Asrc + (A_PER_B ? b * C_ * C_ : 0);
  #pragma unroll
  for (int j = 0; j < 18; ++j){
    const int pi = j * 256 + t;
    const int row = pi / 48, c2 = (pi - row * 48) * 2;
    const float a0 = Ab[row * 96 + c2], a1 = Ab[row * 96 + c2 + 1];
    *(unsigned*)(aw + row * 104 + c2) = (unsigned)f2b(a0) | ((unsigned)f2b(a1) << 16);
  }
  // stage B tile transposed: thread t = pixel p0+t
  if (IN_BF16){
    const unsigned short* Vb = (const unsigned short*)Bsrc + (size_t)b * C_ * HW_ + p0 + t;
    #pragma unroll 8
    for (int c2 = 0; c2 < 48; ++c2){
      const unsigned lo = Vb[(size_t)(2 * c2) * HW_];
      const unsigned hi = Vb[(size_t)(2 * c2 + 1) * HW_];
      *(unsigned*)(xT + t * 104 + 2 * c2) = lo | (hi << 16);
    }
  } else {
    const float* Xb = (const float*)Bsrc + (size_t)b * C_ * HW_ + p0 + t;
    #pragma unroll 8
    for (int c2 = 0; c2 < 48; ++c2){
      const float lo = Xb[(size_t)(2 * c2) * HW_];
      const float hi = Xb[(size_t)(2 * c2 + 1) * HW_];
      *(unsigned*)(xT + t * 104 + 2 * c2) = (unsigned)f2b(lo) | ((unsigned)f2b(hi) << 16);
    }
  }
  __syncthreads();

  f32x4 acc[6][4];
  #pragma unroll
  for (int i = 0; i < 6; ++i)
    #pragma unroll
    for (int j = 0; j < 4; ++j){ acc[i][j][0]=0.f; acc[i][j][1]=0.f; acc[i][j][2]=0.f; acc[i][j][3]=0.f; }

  #pragma unroll
  for (int ks = 0; ks < 3; ++ks){
    short8 a[6];
    #pragma unroll
    for (int mt = 0; mt < 6; ++mt)
      a[mt] = *(const short8*)(aw + (mt * 16 + l15) * 104 + ks * 32 + l4 * 8);
    #pragma unroll
    for (int nt = 0; nt < 4; ++nt){
      const short8 bv = *(const short8*)(xT + (w * 64 + nt * 16 + l15) * 104 + ks * 32 + l4 * 8);
      #pragma unroll
      for (int mt = 0; mt < 6; ++mt)
        acc[mt][nt] = __builtin_amdgcn_mfma_f32_16x16x32_bf16(a[mt], bv, acc[mt][nt], 0, 0, 0);
    }
  }

  if (OUT_F32){
    float* D = (float*)Dst + (size_t)b * C_ * HW_ + p0;
    #pragma unroll
    for (int mt = 0; mt < 6; ++mt)
      #pragma unroll
      for (int nt = 0; nt < 4; ++nt)
        #pragma unroll
        for (int r = 0; r < 4; ++r)
          D[(size_t)(mt * 16 + l4 * 4 + r) * HW_ + w * 64 + nt * 16 + l15] = acc[mt][nt][r];
  } else {
    __syncthreads();                 // all waves done reading xT/aw
    unsigned short* hl = xT;         // reuse as [96][260] (49,920 B), conflict-free
    #pragma unroll
    for (int mt = 0; mt < 6; ++mt)
      #pragma unroll
      for (int nt = 0; nt < 4; ++nt)
        #pragma unroll
        for (int r = 0; r < 4; ++r)
          hl[(mt * 16 + l4 * 4 + r) * 260 + w * 64 + nt * 16 + l15] = f2b(acc[mt][nt][r]);
    __syncthreads();
    unsigned short* D = (unsigned short*)Dst + (size_t)b * C_ * HW_ + p0;
    const int tt = t & 127, mg = t >> 7;
    #pragma unroll 8
    for (int dm = 0; dm < 48; ++dm){
      const int m = mg * 48 + dm;
      const unsigned uv = *(const unsigned*)(hl + m * 260 + 2 * tt);
      *(unsigned*)(D + (size_t)m * HW_ + 2 * tt) = uv;
    }
  }
}

// ---------------- k_dwise: q = x + dw3x3(h) + norm partials ----------------
// grid (24 row-tiles, 6 ch-groups, 8 b), block 256 = 16ch x 8row x 2half.
// No LDS staging: h halo reads are L1/L2-hot. Deterministic tree-reduced norms.
template<int NORM>
__global__ __launch_bounds__(256)
void k_dwise(const unsigned short* __restrict__ hsrc, const float* __restrict__ xsrc,
             const float* __restrict__ dwt, unsigned short* __restrict__ outq,
             float* __restrict__ nrm)
{
  const int t = threadIdx.x;
  const int rt = blockIdx.x, chg = blockIdx.y, b = blockIdx.z;
  const int chl = t >> 4, row = (t >> 1) & 7, half = t & 1;
  const int ch = chg * 16 + chl;
  const int gy = rt * 8 + row;
  float wv[9];
  #pragma unroll
  for (int i = 0; i < 9; ++i) wv[i] = dwt[ch * 9 + i];
  const size_t cbase = ((size_t)b * C_ + ch) * HW_;
  float ssq = 0.f;

  #pragma unroll 1
  for (int ss = 0; ss < 6; ++ss){
    const int col0 = half * 96 + ss * 16;
    float acc[16];
    {
      const float4* xr = (const float4*)(xsrc + cbase + gy * W_ + col0);
      #pragma unroll
      for (int i = 0; i < 4; ++i){
        const float4 f = xr[i];
        acc[4*i] = f.x; acc[4*i+1] = f.y; acc[4*i+2] = f.z; acc[4*i+3] = f.w;
      }
    }
    #pragma unroll
    for (int dy = 0; dy < 3; ++dy){
      const int gyy = gy + dy - 1;
      float hv[20];
      if (gyy >= 0 && gyy < 192){
        const unsigned* hp = (const unsigned*)(hsrc + cbase + (size_t)gyy * W_);
        const int d0 = col0 / 2 - 1;
        #pragma unroll
        for (int dd = 0; dd < 10; ++dd){
          const int d = d0 + dd;
          const unsigned u = (d >= 0 && d < 96) ? hp[d] : 0u;
          hv[2*dd] = blo(u); hv[2*dd+1] = bhi(u);
        }
      } else {
        #pragma unroll
        for (int i = 0; i < 20; ++i) hv[i] = 0.f;
      }
      #pragma unroll
      for (int dx = 0; dx < 3; ++dx){
        const float ww = wv[dy * 3 + dx];
        #pragma unroll
        for (int i = 0; i < 16; ++i) acc[i] = fmaf(ww, hv[i + dx + 1], acc[i]);
      }
    }
    if (NORM){
      #pragma unroll
      for (int i = 0; i < 16; ++i) ssq = fmaf(acc[i], acc[i], ssq);
    }
    unsigned pk[8];
    #pragma unroll
    for (int i = 0; i < 8; ++i)
      pk[i] = (unsigned)f2b(acc[2*i]) | ((unsigned)f2b(acc[2*i+1]) << 16);
    uint4* op = (uint4*)(outq + cbase + gy * W_ + col0);
    op[0] = make_uint4(pk[0], pk[1], pk[2], pk[3]);
    op[1] = make_uint4(pk[4], pk[5], pk[6], pk[7]);
  }
  if (NORM){
    #pragma unroll
    for (int off = 8; off; off >>= 1) ssq += __shfl_xor(ssq, off);
    if ((t & 15) == 0) nrm[((size_t)b * 24 + rt) * C_ + ch] = ssq;
  }
}

// ---------------- k_gram: G[b,h] = q_bh @ k_bh^T ----------------
// grid (24 ns, 24 bh), block 256 (4 waves). Per block: 1536-pixel chunk,
// 3 rounds of 512-pixel panels [32ch][520pix] (straight-copy staging, no
// transpose). Waves interleave K-steps s = 4j+w. Partials summed in k_attn.
__global__ __launch_bounds__(256, 2)
void k_gram(const unsigned short* __restrict__ qb, const unsigned short* __restrict__ kb,
            float* __restrict__ Gp)
{
  __shared__ unsigned short pan[2][32 * 520];   // 66,560 B
  const int t = threadIdx.x, lane = t & 63, w = t >> 6;
  const int ns = blockIdx.x, bh = blockIdx.y;
  const int b = bh / 3, h = bh - b * 3;
  const size_t base = ((size_t)b * C_ + h * 32) * HW_ + ns * 1536;
  const int l31 = lane & 31, l5 = lane >> 5;

  f32x16 acc;
  #pragma unroll
  for (int r = 0; r < 16; ++r) acc[r] = 0.f;

  #pragma unroll 1
  for (int rd = 0; rd < 3; ++rd){
    __syncthreads();
    #pragma unroll 8
    for (int j = 0; j < 64; ++j){
      const int idx = j * 256 + t;            // dword index, 0..16383
      const int op = idx >> 13;               // 0: q, 1: k (uniform per j)
      const int rem = idx & 8191;
      const int ch = rem >> 8, dcol = rem & 255;
      const unsigned* src = (const unsigned*)((op ? kb : qb) + base + (size_t)ch * HW_ + rd * 512) + dcol;
      *(unsigned*)(&pan[op][ch * 520 + dcol * 2]) = *src;
    }
    __syncthreads();
    #pragma unroll
    for (int j8 = 0; j8 < 8; ++j8){
      const int s = j8 * 4 + w;
      const short8 av = *(const short8*)(&pan[0][l31 * 520 + s * 16 + l5 * 8]);
      const short8 bv = *(const short8*)(&pan[1][l31 * 520 + s * 16 + l5 * 8]);
      acc = __builtin_amdgcn_mfma_f32_32x32x16_bf16(av, bv, acc, 0, 0, 0);
    }
  }
  __syncthreads();
  float* red = (float*)pan;                   // 4 x 1024 f32
  #pragma unroll
  for (int r = 0; r < 16; ++r) red[w * 1024 + r * 64 + lane] = acc[r];
  __syncthreads();
  #pragma unroll
  for (int q = 0; q < 4; ++q){
    const int fi = q * 256 + t;
    const float v = red[fi] + red[1024 + fi] + red[2048 + fi] + red[3072 + fi];
    const int rr = fi >> 6, ll = fi & 63;
    const int c = (rr & 3) + 8 * (rr >> 2) + 4 * (ll >> 5);   // m101 C-layout
    const int d = ll & 31;
    Gp[(((size_t)ns * 24 + bh) * 32 + c) * 32 + d] = v;
  }
}

// ---------------- k_attn: norms + softmax + M = proj @ attn_bd ----------------
__global__ __launch_bounds__(256)
void k_attn(const float* __restrict__ Gp, const float* __restrict__ qqp,
            const float* __restrict__ kkp, const float* __restrict__ temp,
            const float* __restrict__ proj, float* __restrict__ M)
{
  const int b = blockIdx.x, t = threadIdx.x;
  __shared__ float at[3][32][32];
  __shared__ float ninv[2][C_];
  if (t < 2 * C_){
    const int kind = t / C_, r = t - kind * C_;
    const float* P = kind ? kkp : qqp;
    float s = 0.f;
    #pragma unroll
    for (int ns = 0; ns < 24; ++ns) s += P[((size_t)b * 24 + ns) * C_ + r];
    ninv[kind][r] = 1.f / fmaxf(sqrtf(s), 1e-12f);
  }
  __syncthreads();
  for (int idx = t; idx < 3 * 1024; idx += 256){
    const int h = idx >> 10, rem = idx & 1023, cc = rem >> 5, dd = rem & 31;
    float g = 0.f;
    #pragma unroll
    for (int ns = 0; ns < 24; ++ns)
      g += Gp[(((size_t)ns * 24 + b * 3 + h) * 32 + cc) * 32 + dd];
    at[h][cc][dd] = g * ninv[0][h * 32 + cc] * ninv[1][h * 32 + dd] * temp[h];
  }
  __syncthreads();
  if (t < C_){
    const int h = t >> 5, cc = t & 31;
    float m = -1e30f;
    for (int dd = 0; dd < 32; ++dd) m = fmaxf(m, at[h][cc][dd]);
    float s = 0.f;
    for (int dd = 0; dd < 32; ++dd){ const float e = expf(at[h][cc][dd] - m); at[h][cc][dd] = e; s += e; }
    const float inv = 1.f / s;
    for (int dd = 0; dd < 32; ++dd) at[h][cc][dd] *= inv;
  }
  __syncthreads();
  for (int idx = t; idx < C_ * C_; idx += 256){
    const int o = idx / 96, hd = idx - o * 96, h = hd >> 5, dd = hd & 31;
    float m = 0.f;
    #pragma unroll
    for (int cc = 0; cc < 32; ++cc)
      m = fmaf(proj[o * 96 + h * 32 + cc], at[h][cc][dd], m);
    M[(size_t)b * 9216 + idx] = m;
  }
}

extern "C" void kernel_launch(void* const* d_in, const int* in_sizes, int n_in,
                              void* d_out, int out_size, void* d_ws, size_t ws_size,
                              hipStream_t stream)
{
  const float* x     = (const float*)d_in[0];
  const float* y     = (const float*)d_in[1];
  const float* z     = (const float*)d_in[2];
  const float* temp  = (const float*)d_in[3];
  const float* q_pwc = (const float*)d_in[4];
  const float* q_dwc = (const float*)d_in[5];
  const float* k_pwc = (const float*)d_in[6];
  const float* k_dwc = (const float*)d_in[7];
  const float* v_pwc = (const float*)d_in[8];
  const float* v_dwc = (const float*)d_in[9];
  const float* proj  = (const float*)d_in[10];

  // workspace: h shared by all 3 convs (sequential); Gp/M alias dead-h region.
  char* ws = (char*)d_ws;
  unsigned short* hb = (unsigned short*)ws;                    // 56,623,104 B
  unsigned short* qb = (unsigned short*)(ws + 56623104);
  unsigned short* kb = (unsigned short*)(ws + 113246208);
  unsigned short* vb = (unsigned short*)(ws + 169869312);      // end 226,492,416
  float* qqp = (float*)(ws + 226492416);                       // 73,728
  float* kkp = (float*)(ws + 226566144);                       // 73,728
  float* Gp  = (float*)(ws + 4194304);                         // alias hb (dead)
  float* M   = (float*)(ws + 8388608);                         // alias hb (dead)
  float* out = (float*)d_out;

  const dim3 gg(HW_ / 256, B_);
  const dim3 gd(24, 6, B_);
  k_gemm<0,0,0><<<gg, 256, 0, stream>>>(x, q_pwc, hb);
  k_dwise<1><<<gd, 256, 0, stream>>>(hb, x, q_dwc, qb, qqp);
  k_gemm<0,0,0><<<gg, 256, 0, stream>>>(y, k_pwc, hb);
  k_dwise<1><<<gd, 256, 0, stream>>>(hb, y, k_dwc, kb, kkp);
  k_gemm<0,0,0><<<gg, 256, 0, stream>>>(z, v_pwc, hb);
  k_dwise<0><<<gd, 256, 0, stream>>>(hb, z, v_dwc, vb, nullptr);
  k_gram<<<dim3(24, 24), 256, 0, stream>>>(qb, kb, Gp);
  k_attn<<<B_, 256, 0, stream>>>(Gp, qqp, kkp, temp, proj, M);
  k_gemm<1,1,1><<<gg, 256, 0, stream>>>(vb, M, out);
}

// Round 6
// 476.493 us; speedup vs baseline: 5.8745x; 1.3409x over previous
//
#include <hip/hip_runtime.h>

// CrossAttention MI355X — round 6 (= round-5 design, dead HH_CHECK line removed).
//  k_gemm<0,0,0> x3 : h = pw @ x          (bf16 out via LDS-transpose epilogue)
//  k_dwise<NORM> x3 : q/k/v = x + dw3x3(h), fused L2-norm partials (q,k)
//  k_gram           : G[b,h] = q @ k^T    (32x32x16 MFMA, straight-copy panels)
//  k_attn           : norms + softmax + M[b] = proj @ attn_blockdiag
//  k_gemm<1,1,1>    : out = M[b] @ v      (f32 direct epilogue)

#define B_  8
#define C_  96
#define W_  192
#define HW_ 36864
#define NB_ 8      // row-bands per image in k_dwise (24 rows each)

typedef __attribute__((ext_vector_type(8)))  short short8;
typedef __attribute__((ext_vector_type(4)))  float f32x4;
typedef __attribute__((ext_vector_type(16))) float f32x16;

__device__ __forceinline__ unsigned short f2b(float f){
  unsigned u = __float_as_uint(f);
  u += 0x7fffu + ((u >> 16) & 1u);
  return (unsigned short)(u >> 16);
}
__device__ __forceinline__ float blo(unsigned u){ return __uint_as_float(u << 16); }
__device__ __forceinline__ float bhi(unsigned u){ return __uint_as_float(u & 0xffff0000u); }
__device__ __forceinline__ float b2f(unsigned short v){ return __uint_as_float((unsigned)v << 16); }

// ---------------- k_gemm: D[96][36864] = A(96x96) @ B(96x36864) per batch ----
// grid (144, 8), block 256 (4 waves). Wave w owns pixels [w*64, w*64+64).
template<int OUT_F32, int IN_BF16, int A_PER_B>
__global__ __launch_bounds__(256, 2)
void k_gemm(const void* __restrict__ Bsrc, const float* __restrict__ Asrc,
            void* __restrict__ Dst)
{
  __shared__ unsigned short xT[256 * 104];   // 53,248 B  [pix][ch]
  __shared__ unsigned short aw[96 * 104];    // 19,968 B  [m][k]
  const int t = threadIdx.x;
  const int b = blockIdx.y;
  const int p0 = blockIdx.x * 256;
  const int lane = t & 63, w = t >> 6;
  const int l15 = lane & 15, l4 = lane >> 4;

  // stage A: f32 -> bf16 pairs
  const float* Ab = Asrc + (A_PER_B ? b * C_ * C_ : 0);
  #pragma unroll
  for (int j = 0; j < 18; ++j){
    const int pi = j * 256 + t;
    const int row = pi / 48, c2 = (pi - row * 48) * 2;
    const float a0 = Ab[row * 96 + c2], a1 = Ab[row * 96 + c2 + 1];
    *(unsigned*)(aw + row * 104 + c2) = (unsigned)f2b(a0) | ((unsigned)f2b(a1) << 16);
  }
  // stage B tile transposed: thread t = pixel p0+t
  if (IN_BF16){
    const unsigned short* Vb = (const unsigned short*)Bsrc + (size_t)b * C_ * HW_ + p0 + t;
    #pragma unroll 8
    for (int c2 = 0; c2 < 48; ++c2){
      const unsigned lo = Vb[(size_t)(2 * c2) * HW_];
      const unsigned hi = Vb[(size_t)(2 * c2 + 1) * HW_];
      *(unsigned*)(xT + t * 104 + 2 * c2) = lo | (hi << 16);
    }
  } else {
    const float* Xb = (const float*)Bsrc + (size_t)b * C_ * HW_ + p0 + t;
    #pragma unroll 8
    for (int c2 = 0; c2 < 48; ++c2){
      const float lo = Xb[(size_t)(2 * c2) * HW_];
      const float hi = Xb[(size_t)(2 * c2 + 1) * HW_];
      *(unsigned*)(xT + t * 104 + 2 * c2) = (unsigned)f2b(lo) | ((unsigned)f2b(hi) << 16);
    }
  }
  __syncthreads();

  f32x4 acc[6][4];
  #pragma unroll
  for (int i = 0; i < 6; ++i)
    #pragma unroll
    for (int j = 0; j < 4; ++j){ acc[i][j][0]=0.f; acc[i][j][1]=0.f; acc[i][j][2]=0.f; acc[i][j][3]=0.f; }

  #pragma unroll
  for (int ks = 0; ks < 3; ++ks){
    short8 a[6];
    #pragma unroll
    for (int mt = 0; mt < 6; ++mt)
      a[mt] = *(const short8*)(aw + (mt * 16 + l15) * 104 + ks * 32 + l4 * 8);
    #pragma unroll
    for (int nt = 0; nt < 4; ++nt){
      const short8 bv = *(const short8*)(xT + (w * 64 + nt * 16 + l15) * 104 + ks * 32 + l4 * 8);
      #pragma unroll
      for (int mt = 0; mt < 6; ++mt)
        acc[mt][nt] = __builtin_amdgcn_mfma_f32_16x16x32_bf16(a[mt], bv, acc[mt][nt], 0, 0, 0);
    }
  }

  if (OUT_F32){
    float* D = (float*)Dst + (size_t)b * C_ * HW_ + p0;
    #pragma unroll
    for (int mt = 0; mt < 6; ++mt)
      #pragma unroll
      for (int nt = 0; nt < 4; ++nt)
        #pragma unroll
        for (int r = 0; r < 4; ++r)
          D[(size_t)(mt * 16 + l4 * 4 + r) * HW_ + w * 64 + nt * 16 + l15] = acc[mt][nt][r];
  } else {
    __syncthreads();                 // all waves done reading xT/aw
    unsigned short* hl = xT;         // reuse as [96][260], conflict-free
    #pragma unroll
    for (int mt = 0; mt < 6; ++mt)
      #pragma unroll
      for (int nt = 0; nt < 4; ++nt)
        #pragma unroll
        for (int r = 0; r < 4; ++r)
          hl[(mt * 16 + l4 * 4 + r) * 260 + w * 64 + nt * 16 + l15] = f2b(acc[mt][nt][r]);
    __syncthreads();
    unsigned short* D = (unsigned short*)Dst + (size_t)b * C_ * HW_ + p0;
    const int tt = t & 127, mg = t >> 7;
    #pragma unroll 8
    for (int dm = 0; dm < 48; ++dm){
      const int m = mg * 48 + dm;
      const unsigned uv = *(const unsigned*)(hl + m * 260 + 2 * tt);
      *(unsigned*)(D + (size_t)m * HW_ + 2 * tt) = uv;
    }
  }
}

// ---------------- k_dwise: q = x + dw3x3(h), lane = column ----------------
// grid (NB_ bands, 96 ch, 8 b), block 192 (3 waves). Fully coalesced rows:
// lane c reads x[r][c] (f32), 3 new h values per row (register rotation),
// writes q[r][c] (bf16). Norm partials per (b,band,ch), tree-reduced.
template<int NORM>
__global__ __launch_bounds__(192)
void k_dwise(const unsigned short* __restrict__ hsrc, const float* __restrict__ xsrc,
             const float* __restrict__ dwt, unsigned short* __restrict__ outq,
             float* __restrict__ nrm)
{
  const int c    = threadIdx.x;            // column 0..191
  const int band = blockIdx.x;
  const int ch   = blockIdx.y;
  const int b    = blockIdx.z;
  const size_t cbase = ((size_t)b * C_ + ch) * HW_;
  float w[9];
  #pragma unroll
  for (int i = 0; i < 9; ++i) w[i] = dwt[ch * 9 + i];   // block-uniform -> s_load

  const int r0 = band * 24;
  float hm[3], hc[3], hn[3];
  {
    const int rm = r0 - 1;
    if (rm >= 0){
      const unsigned short* hp = hsrc + cbase + (size_t)rm * W_;
      hm[0] = (c > 0)       ? b2f(hp[c-1]) : 0.f;
      hm[1] = b2f(hp[c]);
      hm[2] = (c < W_ - 1)  ? b2f(hp[c+1]) : 0.f;
    } else { hm[0] = hm[1] = hm[2] = 0.f; }
    const unsigned short* hp = hsrc + cbase + (size_t)r0 * W_;
    hc[0] = (c > 0)       ? b2f(hp[c-1]) : 0.f;
    hc[1] = b2f(hp[c]);
    hc[2] = (c < W_ - 1)  ? b2f(hp[c+1]) : 0.f;
  }

  float ssq = 0.f;
  #pragma unroll 4
  for (int r = r0; r < r0 + 24; ++r){
    const int rn = r + 1;
    if (rn < 192){
      const unsigned short* hp = hsrc + cbase + (size_t)rn * W_;
      hn[0] = (c > 0)       ? b2f(hp[c-1]) : 0.f;
      hn[1] = b2f(hp[c]);
      hn[2] = (c < W_ - 1)  ? b2f(hp[c+1]) : 0.f;
    } else { hn[0] = hn[1] = hn[2] = 0.f; }

    float acc = xsrc[cbase + (size_t)r * W_ + c];
    acc = fmaf(w[0], hm[0], acc); acc = fmaf(w[1], hm[1], acc); acc = fmaf(w[2], hm[2], acc);
    acc = fmaf(w[3], hc[0], acc); acc = fmaf(w[4], hc[1], acc); acc = fmaf(w[5], hc[2], acc);
    acc = fmaf(w[6], hn[0], acc); acc = fmaf(w[7], hn[1], acc); acc = fmaf(w[8], hn[2], acc);
    if (NORM) ssq = fmaf(acc, acc, ssq);
    outq[cbase + (size_t)r * W_ + c] = f2b(acc);

    hm[0]=hc[0]; hm[1]=hc[1]; hm[2]=hc[2];
    hc[0]=hn[0]; hc[1]=hn[1]; hc[2]=hn[2];
  }

  if (NORM){
    #pragma unroll
    for (int off = 32; off; off >>= 1) ssq += __shfl_xor(ssq, off);
    __shared__ float red[3];
    if ((c & 63) == 0) red[c >> 6] = ssq;
    __syncthreads();
    if (c == 0)
      nrm[((size_t)b * NB_ + band) * C_ + ch] = red[0] + red[1] + red[2];
  }
}

// ---------------- k_gram: G[b,h] = q_bh @ k_bh^T ----------------
__global__ __launch_bounds__(256, 2)
void k_gram(const unsigned short* __restrict__ qb, const unsigned short* __restrict__ kb,
            float* __restrict__ Gp)
{
  __shared__ unsigned short pan[2][32 * 520];   // 66,560 B
  const int t = threadIdx.x, lane = t & 63, w = t >> 6;
  const int ns = blockIdx.x, bh = blockIdx.y;
  const int b = bh / 3, h = bh - b * 3;
  const size_t base = ((size_t)b * C_ + h * 32) * HW_ + ns * 1536;
  const int l31 = lane & 31, l5 = lane >> 5;

  f32x16 acc;
  #pragma unroll
  for (int r = 0; r < 16; ++r) acc[r] = 0.f;

  #pragma unroll 1
  for (int rd = 0; rd < 3; ++rd){
    __syncthreads();
    #pragma unroll 8
    for (int j = 0; j < 64; ++j){
      const int idx = j * 256 + t;
      const int op = idx >> 13;
      const int rem = idx & 8191;
      const int ch = rem >> 8, dcol = rem & 255;
      const unsigned* src = (const unsigned*)((op ? kb : qb) + base + (size_t)ch * HW_ + rd * 512) + dcol;
      *(unsigned*)(&pan[op][ch * 520 + dcol * 2]) = *src;
    }
    __syncthreads();
    #pragma unroll
    for (int j8 = 0; j8 < 8; ++j8){
      const int s = j8 * 4 + w;
      const short8 av = *(const short8*)(&pan[0][l31 * 520 + s * 16 + l5 * 8]);
      const short8 bv = *(const short8*)(&pan[1][l31 * 520 + s * 16 + l5 * 8]);
      acc = __builtin_amdgcn_mfma_f32_32x32x16_bf16(av, bv, acc, 0, 0, 0);
    }
  }
  __syncthreads();
  float* red = (float*)pan;
  #pragma unroll
  for (int r = 0; r < 16; ++r) red[w * 1024 + r * 64 + lane] = acc[r];
  __syncthreads();
  #pragma unroll
  for (int q = 0; q < 4; ++q){
    const int fi = q * 256 + t;
    const float v = red[fi] + red[1024 + fi] + red[2048 + fi] + red[3072 + fi];
    const int rr = fi >> 6, ll = fi & 63;
    const int c = (rr & 3) + 8 * (rr >> 2) + 4 * (ll >> 5);   // m101 C-layout
    const int d = ll & 31;
    Gp[(((size_t)ns * 24 + bh) * 32 + c) * 32 + d] = v;
  }
}

// ---------------- k_attn: norms + softmax + M = proj @ attn_bd ----------------
__global__ __launch_bounds__(256)
void k_attn(const float* __restrict__ Gp, const float* __restrict__ qqp,
            const float* __restrict__ kkp, const float* __restrict__ temp,
            const float* __restrict__ proj, float* __restrict__ M)
{
  const int b = blockIdx.x, t = threadIdx.x;
  __shared__ float at[3][32][32];
  __shared__ float ninv[2][C_];
  if (t < 2 * C_){
    const int kind = t / C_, r = t - kind * C_;
    const float* P = kind ? kkp : qqp;
    float s = 0.f;
    #pragma unroll
    for (int ns = 0; ns < NB_; ++ns) s += P[((size_t)b * NB_ + ns) * C_ + r];
    ninv[kind][r] = 1.f / fmaxf(sqrtf(s), 1e-12f);
  }
  __syncthreads();
  for (int idx = t; idx < 3 * 1024; idx += 256){
    const int h = idx >> 10, rem = idx & 1023, cc = rem >> 5, dd = rem & 31;
    float g = 0.f;
    #pragma unroll
    for (int ns = 0; ns < 24; ++ns)
      g += Gp[(((size_t)ns * 24 + b * 3 + h) * 32 + cc) * 32 + dd];
    at[h][cc][dd] = g * ninv[0][h * 32 + cc] * ninv[1][h * 32 + dd] * temp[h];
  }
  __syncthreads();
  if (t < C_){
    const int h = t >> 5, cc = t & 31;
    float m = -1e30f;
    for (int dd = 0; dd < 32; ++dd) m = fmaxf(m, at[h][cc][dd]);
    float s = 0.f;
    for (int dd = 0; dd < 32; ++dd){ const float e = expf(at[h][cc][dd] - m); at[h][cc][dd] = e; s += e; }
    const float inv = 1.f / s;
    for (int dd = 0; dd < 32; ++dd) at[h][cc][dd] *= inv;
  }
  __syncthreads();
  for (int idx = t; idx < C_ * C_; idx += 256){
    const int o = idx / 96, hd = idx - o * 96, h = hd >> 5, dd = hd & 31;
    float m = 0.f;
    #pragma unroll
    for (int cc = 0; cc < 32; ++cc)
      m = fmaf(proj[o * 96 + h * 32 + cc], at[h][cc][dd], m);
    M[(size_t)b * 9216 + idx] = m;
  }
}

extern "C" void kernel_launch(void* const* d_in, const int* in_sizes, int n_in,
                              void* d_out, int out_size, void* d_ws, size_t ws_size,
                              hipStream_t stream)
{
  const float* x     = (const float*)d_in[0];
  const float* y     = (const float*)d_in[1];
  const float* z     = (const float*)d_in[2];
  const float* temp  = (const float*)d_in[3];
  const float* q_pwc = (const float*)d_in[4];
  const float* q_dwc = (const float*)d_in[5];
  const float* k_pwc = (const float*)d_in[6];
  const float* k_dwc = (const float*)d_in[7];
  const float* v_pwc = (const float*)d_in[8];
  const float* v_dwc = (const float*)d_in[9];
  const float* proj  = (const float*)d_in[10];

  // workspace: h shared by all 3 convs (sequential); Gp/M alias dead-h region.
  char* ws = (char*)d_ws;
  unsigned short* hb = (unsigned short*)ws;                    // 56,623,104 B
  unsigned short* qb = (unsigned short*)(ws + 56623104);
  unsigned short* kb = (unsigned short*)(ws + 113246208);
  unsigned short* vb = (unsigned short*)(ws + 169869312);      // end 226,492,416
  float* qqp = (float*)(ws + 226492416);                       // 24,576
  float* kkp = (float*)(ws + 226517120);                       // 24,576 (16B-aligned)
  float* Gp  = (float*)(ws + 4194304);                         // alias hb (dead)
  float* M   = (float*)(ws + 8388608);                         // alias hb (dead)
  float* out = (float*)d_out;

  const dim3 gg(HW_ / 256, B_);
  const dim3 gd(NB_, C_, B_);
  k_gemm<0,0,0><<<gg, 256, 0, stream>>>(x, q_pwc, hb);
  k_dwise<1><<<gd, 192, 0, stream>>>(hb, x, q_dwc, qb, qqp);
  k_gemm<0,0,0><<<gg, 256, 0, stream>>>(y, k_pwc, hb);
  k_dwise<1><<<gd, 192, 0, stream>>>(hb, y, k_dwc, kb, kkp);
  k_gemm<0,0,0><<<gg, 256, 0, stream>>>(z, v_pwc, hb);
  k_dwise<0><<<gd, 192, 0, stream>>>(hb, z, v_dwc, vb, nullptr);
  k_gram<<<dim3(24, 24), 256, 0, stream>>>(qb, kb, Gp);
  k_attn<<<B_, 256, 0, stream>>>(Gp, qqp, kkp, temp, proj, M);
  k_gemm<1,1,1><<<gg, 256, 0, stream>>>(vb, M, out);
}

// Round 7
// 347.230 us; speedup vs baseline: 8.0615x; 1.3723x over previous
//
#include <hip/hip_runtime.h>

// CrossAttention MI355X — round 7: vmem-issue-bound k_dwise widened to
// 4 cols/lane (uint2 h-loads + shfl halo exchange; 3 vmem/row vs 20).
//  k_gemm<0,0,0> x3 : h = pw @ x          (bf16 out via LDS-transpose epilogue)
//  k_dwise<NORM> x3 : q/k/v = x + dw3x3(h), fused L2-norm partials (q,k)
//  k_gram           : G[b,h] = q @ k^T    (32x32x16 MFMA, straight-copy panels)
//  k_attn           : norms + softmax + M[b] = proj @ attn_blockdiag
//  k_gemm<1,1,1>    : out = M[b] @ v      (f32 direct epilogue)

#define B_  8
#define C_  96
#define W_  192
#define HW_ 36864
#define NB_ 8      // row-bands per image in k_dwise (24 rows each)

typedef __attribute__((ext_vector_type(8)))  short short8;
typedef __attribute__((ext_vector_type(4)))  float f32x4;
typedef __attribute__((ext_vector_type(16))) float f32x16;

__device__ __forceinline__ unsigned short f2b(float f){
  unsigned u = __float_as_uint(f);
  u += 0x7fffu + ((u >> 16) & 1u);
  return (unsigned short)(u >> 16);
}
__device__ __forceinline__ float blo(unsigned u){ return __uint_as_float(u << 16); }
__device__ __forceinline__ float bhi(unsigned u){ return __uint_as_float(u & 0xffff0000u); }

// ---------------- k_gemm: D[96][36864] = A(96x96) @ B(96x36864) per batch ----
// grid (144, 8), block 256 (4 waves). Wave w owns pixels [w*64, w*64+64).
template<int OUT_F32, int IN_BF16, int A_PER_B>
__global__ __launch_bounds__(256, 2)
void k_gemm(const void* __restrict__ Bsrc, const float* __restrict__ Asrc,
            void* __restrict__ Dst)
{
  __shared__ unsigned short xT[256 * 104];   // 53,248 B  [pix][ch]
  __shared__ unsigned short aw[96 * 104];    // 19,968 B  [m][k]
  const int t = threadIdx.x;
  const int b = blockIdx.y;
  const int p0 = blockIdx.x * 256;
  const int lane = t & 63, w = t >> 6;
  const int l15 = lane & 15, l4 = lane >> 4;

  // stage A: f32 -> bf16 pairs
  const float* Ab = Asrc + (A_PER_B ? b * C_ * C_ : 0);
  #pragma unroll
  for (int j = 0; j < 18; ++j){
    const int pi = j * 256 + t;
    const int row = pi / 48, c2 = (pi - row * 48) * 2;
    const float a0 = Ab[row * 96 + c2], a1 = Ab[row * 96 + c2 + 1];
    *(unsigned*)(aw + row * 104 + c2) = (unsigned)f2b(a0) | ((unsigned)f2b(a1) << 16);
  }
  // stage B tile transposed: thread t = pixel p0+t
  if (IN_BF16){
    const unsigned short* Vb = (const unsigned short*)Bsrc + (size_t)b * C_ * HW_ + p0 + t;
    #pragma unroll 8
    for (int c2 = 0; c2 < 48; ++c2){
      const unsigned lo = Vb[(size_t)(2 * c2) * HW_];
      const unsigned hi = Vb[(size_t)(2 * c2 + 1) * HW_];
      *(unsigned*)(xT + t * 104 + 2 * c2) = lo | (hi << 16);
    }
  } else {
    const float* Xb = (const float*)Bsrc + (size_t)b * C_ * HW_ + p0 + t;
    #pragma unroll 8
    for (int c2 = 0; c2 < 48; ++c2){
      const float lo = Xb[(size_t)(2 * c2) * HW_];
      const float hi = Xb[(size_t)(2 * c2 + 1) * HW_];
      *(unsigned*)(xT + t * 104 + 2 * c2) = (unsigned)f2b(lo) | ((unsigned)f2b(hi) << 16);
    }
  }
  __syncthreads();

  f32x4 acc[6][4];
  #pragma unroll
  for (int i = 0; i < 6; ++i)
    #pragma unroll
    for (int j = 0; j < 4; ++j){ acc[i][j][0]=0.f; acc[i][j][1]=0.f; acc[i][j][2]=0.f; acc[i][j][3]=0.f; }

  #pragma unroll
  for (int ks = 0; ks < 3; ++ks){
    short8 a[6];
    #pragma unroll
    for (int mt = 0; mt < 6; ++mt)
      a[mt] = *(const short8*)(aw + (mt * 16 + l15) * 104 + ks * 32 + l4 * 8);
    #pragma unroll
    for (int nt = 0; nt < 4; ++nt){
      const short8 bv = *(const short8*)(xT + (w * 64 + nt * 16 + l15) * 104 + ks * 32 + l4 * 8);
      #pragma unroll
      for (int mt = 0; mt < 6; ++mt)
        acc[mt][nt] = __builtin_amdgcn_mfma_f32_16x16x32_bf16(a[mt], bv, acc[mt][nt], 0, 0, 0);
    }
  }

  if (OUT_F32){
    float* D = (float*)Dst + (size_t)b * C_ * HW_ + p0;
    #pragma unroll
    for (int mt = 0; mt < 6; ++mt)
      #pragma unroll
      for (int nt = 0; nt < 4; ++nt)
        #pragma unroll
        for (int r = 0; r < 4; ++r)
          D[(size_t)(mt * 16 + l4 * 4 + r) * HW_ + w * 64 + nt * 16 + l15] = acc[mt][nt][r];
  } else {
    __syncthreads();                 // all waves done reading xT/aw
    unsigned short* hl = xT;         // reuse as [96][260], conflict-free
    #pragma unroll
    for (int mt = 0; mt < 6; ++mt)
      #pragma unroll
      for (int nt = 0; nt < 4; ++nt)
        #pragma unroll
        for (int r = 0; r < 4; ++r)
          hl[(mt * 16 + l4 * 4 + r) * 260 + w * 64 + nt * 16 + l15] = f2b(acc[mt][nt][r]);
    __syncthreads();
    unsigned short* D = (unsigned short*)Dst + (size_t)b * C_ * HW_ + p0;
    const int tt = t & 127, mg = t >> 7;
    #pragma unroll 8
    for (int dm = 0; dm < 48; ++dm){
      const int m = mg * 48 + dm;
      const unsigned uv = *(const unsigned*)(hl + m * 260 + 2 * tt);
      *(unsigned*)(D + (size_t)m * HW_ + 2 * tt) = uv;
    }
  }
}

// ---------------- k_dwise: q = x + dw3x3(h), 4 cols/lane ----------------
// grid (NB_ bands, 96 ch, 8 b), block 256 (4 waves). Wave wv = 6-row strip;
// lanes 0..47 active, lane g covers cols 4g..4g+3. Per row: 1 uint2 h-load
// (+2 shfl for halo cols), 1 float4 x-load, 1 uint2 bf16 store.
template<int NORM>
__global__ __launch_bounds__(256)
void k_dwise(const unsigned short* __restrict__ hsrc, const float* __restrict__ xsrc,
             const float* __restrict__ dwt, unsigned short* __restrict__ outq,
             float* __restrict__ nrm)
{
  const int t = threadIdx.x;
  const int lane = t & 63, wv = t >> 6;
  const int band = blockIdx.x, ch = blockIdx.y, b = blockIdx.z;
  const size_t cbase = ((size_t)b * C_ + ch) * HW_;
  __shared__ float red[4];
  float ssq = 0.f;

  if (lane < 48){
    const int g = lane;
    float w[9];
    #pragma unroll
    for (int i = 0; i < 9; ++i) w[i] = dwt[ch * 9 + i];   // block-uniform -> s_load
    const int r0 = band * 24 + wv * 6;

    float hm[6], hc[6], hn[6];
#define LOADROW(dst, r)                                                          \
    if ((r) >= 0 && (r) < 192){                                                  \
      const uint2 u = *(const uint2*)(hsrc + cbase + (size_t)(r) * W_ + g * 4);  \
      dst[1] = blo(u.x); dst[2] = bhi(u.x); dst[3] = blo(u.y); dst[4] = bhi(u.y);\
      const float L = __shfl_up(dst[4], 1);                                      \
      const float R = __shfl_down(dst[1], 1);                                    \
      dst[0] = (g == 0)  ? 0.f : L;                                              \
      dst[5] = (g == 47) ? 0.f : R;                                              \
    } else {                                                                     \
      dst[0]=0.f; dst[1]=0.f; dst[2]=0.f; dst[3]=0.f; dst[4]=0.f; dst[5]=0.f;    \
    }

    LOADROW(hm, r0 - 1)
    LOADROW(hc, r0)

    #pragma unroll
    for (int i = 0; i < 6; ++i){
      const int r = r0 + i;
      LOADROW(hn, r + 1)
      const float4 xv = *(const float4*)(xsrc + cbase + (size_t)r * W_ + g * 4);
      float a[4] = {xv.x, xv.y, xv.z, xv.w};
      #pragma unroll
      for (int j = 0; j < 4; ++j){
        float s = a[j];
        s = fmaf(w[0], hm[j],   s); s = fmaf(w[1], hm[j+1], s); s = fmaf(w[2], hm[j+2], s);
        s = fmaf(w[3], hc[j],   s); s = fmaf(w[4], hc[j+1], s); s = fmaf(w[5], hc[j+2], s);
        s = fmaf(w[6], hn[j],   s); s = fmaf(w[7], hn[j+1], s); s = fmaf(w[8], hn[j+2], s);
        a[j] = s;
        if (NORM) ssq = fmaf(s, s, ssq);
      }
      const unsigned p0 = (unsigned)f2b(a[0]) | ((unsigned)f2b(a[1]) << 16);
      const unsigned p1 = (unsigned)f2b(a[2]) | ((unsigned)f2b(a[3]) << 16);
      *(uint2*)(outq + cbase + (size_t)r * W_ + g * 4) = make_uint2(p0, p1);
      #pragma unroll
      for (int j = 0; j < 6; ++j){ hm[j] = hc[j]; hc[j] = hn[j]; }
    }
#undef LOADROW
  }

  if (NORM){
    #pragma unroll
    for (int off = 32; off; off >>= 1) ssq += __shfl_xor(ssq, off);  // idle lanes add 0
    if (lane == 0) red[wv] = ssq;
    __syncthreads();
    if (t == 0)
      nrm[((size_t)b * NB_ + band) * C_ + ch] = red[0] + red[1] + red[2] + red[3];
  }
}

// ---------------- k_gram: G[b,h] = q_bh @ k_bh^T ----------------
__global__ __launch_bounds__(256, 2)
void k_gram(const unsigned short* __restrict__ qb, const unsigned short* __restrict__ kb,
            float* __restrict__ Gp)
{
  __shared__ unsigned short pan[2][32 * 520];   // 66,560 B
  const int t = threadIdx.x, lane = t & 63, w = t >> 6;
  const int ns = blockIdx.x, bh = blockIdx.y;
  const int b = bh / 3, h = bh - b * 3;
  const size_t base = ((size_t)b * C_ + h * 32) * HW_ + ns * 1536;
  const int l31 = lane & 31, l5 = lane >> 5;

  f32x16 acc;
  #pragma unroll
  for (int r = 0; r < 16; ++r) acc[r] = 0.f;

  #pragma unroll 1
  for (int rd = 0; rd < 3; ++rd){
    __syncthreads();
    #pragma unroll 8
    for (int j = 0; j < 64; ++j){
      const int idx = j * 256 + t;
      const int op = idx >> 13;
      const int rem = idx & 8191;
      const int ch = rem >> 8, dcol = rem & 255;
      const unsigned* src = (const unsigned*)((op ? kb : qb) + base + (size_t)ch * HW_ + rd * 512) + dcol;
      *(unsigned*)(&pan[op][ch * 520 + dcol * 2]) = *src;
    }
    __syncthreads();
    #pragma unroll
    for (int j8 = 0; j8 < 8; ++j8){
      const int s = j8 * 4 + w;
      const short8 av = *(const short8*)(&pan[0][l31 * 520 + s * 16 + l5 * 8]);
      const short8 bv = *(const short8*)(&pan[1][l31 * 520 + s * 16 + l5 * 8]);
      acc = __builtin_amdgcn_mfma_f32_32x32x16_bf16(av, bv, acc, 0, 0, 0);
    }
  }
  __syncthreads();
  float* red = (float*)pan;
  #pragma unroll
  for (int r = 0; r < 16; ++r) red[w * 1024 + r * 64 + lane] = acc[r];
  __syncthreads();
  #pragma unroll
  for (int q = 0; q < 4; ++q){
    const int fi = q * 256 + t;
    const float v = red[fi] + red[1024 + fi] + red[2048 + fi] + red[3072 + fi];
    const int rr = fi >> 6, ll = fi & 63;
    const int c = (rr & 3) + 8 * (rr >> 2) + 4 * (ll >> 5);   // m101 C-layout
    const int d = ll & 31;
    Gp[(((size_t)ns * 24 + bh) * 32 + c) * 32 + d] = v;
  }
}

// ---------------- k_attn: norms + softmax + M = proj @ attn_bd ----------------
__global__ __launch_bounds__(256)
void k_attn(const float* __restrict__ Gp, const float* __restrict__ qqp,
            const float* __restrict__ kkp, const float* __restrict__ temp,
            const float* __restrict__ proj, float* __restrict__ M)
{
  const int b = blockIdx.x, t = threadIdx.x;
  __shared__ float at[3][32][32];
  __shared__ float ninv[2][C_];
  if (t < 2 * C_){
    const int kind = t / C_, r = t - kind * C_;
    const float* P = kind ? kkp : qqp;
    float s = 0.f;
    #pragma unroll
    for (int ns = 0; ns < NB_; ++ns) s += P[((size_t)b * NB_ + ns) * C_ + r];
    ninv[kind][r] = 1.f / fmaxf(sqrtf(s), 1e-12f);
  }
  __syncthreads();
  for (int idx = t; idx < 3 * 1024; idx += 256){
    const int h = idx >> 10, rem = idx & 1023, cc = rem >> 5, dd = rem & 31;
    float g = 0.f;
    #pragma unroll
    for (int ns = 0; ns < 24; ++ns)
      g += Gp[(((size_t)ns * 24 + b * 3 + h) * 32 + cc) * 32 + dd];
    at[h][cc][dd] = g * ninv[0][h * 32 + cc] * ninv[1][h * 32 + dd] * temp[h];
  }
  __syncthreads();
  if (t < C_){
    const int h = t >> 5, cc = t & 31;
    float m = -1e30f;
    for (int dd = 0; dd < 32; ++dd) m = fmaxf(m, at[h][cc][dd]);
    float s = 0.f;
    for (int dd = 0; dd < 32; ++dd){ const float e = expf(at[h][cc][dd] - m); at[h][cc][dd] = e; s += e; }
    const float inv = 1.f / s;
    for (int dd = 0; dd < 32; ++dd) at[h][cc][dd] *= inv;
  }
  __syncthreads();
  for (int idx = t; idx < C_ * C_; idx += 256){
    const int o = idx / 96, hd = idx - o * 96, h = hd >> 5, dd = hd & 31;
    float m = 0.f;
    #pragma unroll
    for (int cc = 0; cc < 32; ++cc)
      m = fmaf(proj[o * 96 + h * 32 + cc], at[h][cc][dd], m);
    M[(size_t)b * 9216 + idx] = m;
  }
}

extern "C" void kernel_launch(void* const* d_in, const int* in_sizes, int n_in,
                              void* d_out, int out_size, void* d_ws, size_t ws_size,
                              hipStream_t stream)
{
  const float* x     = (const float*)d_in[0];
  const float* y     = (const float*)d_in[1];
  const float* z     = (const float*)d_in[2];
  const float* temp  = (const float*)d_in[3];
  const float* q_pwc = (const float*)d_in[4];
  const float* q_dwc = (const float*)d_in[5];
  const float* k_pwc = (const float*)d_in[6];
  const float* k_dwc = (const float*)d_in[7];
  const float* v_pwc = (const float*)d_in[8];
  const float* v_dwc = (const float*)d_in[9];
  const float* proj  = (const float*)d_in[10];

  // workspace: h shared by all 3 convs (sequential); Gp/M alias dead-h region.
  char* ws = (char*)d_ws;
  unsigned short* hb = (unsigned short*)ws;                    // 56,623,104 B
  unsigned short* qb = (unsigned short*)(ws + 56623104);
  unsigned short* kb = (unsigned short*)(ws + 113246208);
  unsigned short* vb = (unsigned short*)(ws + 169869312);      // end 226,492,416
  float* qqp = (float*)(ws + 226492416);                       // 24,576
  float* kkp = (float*)(ws + 226517120);                       // 24,576 (16B-aligned)
  float* Gp  = (float*)(ws + 4194304);                         // alias hb (dead)
  float* M   = (float*)(ws + 8388608);                         // alias hb (dead)
  float* out = (float*)d_out;

  const dim3 gg(HW_ / 256, B_);
  const dim3 gd(NB_, C_, B_);
  k_gemm<0,0,0><<<gg, 256, 0, stream>>>(x, q_pwc, hb);
  k_dwise<1><<<gd, 256, 0, stream>>>(hb, x, q_dwc, qb, qqp);
  k_gemm<0,0,0><<<gg, 256, 0, stream>>>(y, k_pwc, hb);
  k_dwise<1><<<gd, 256, 0, stream>>>(hb, y, k_dwc, kb, kkp);
  k_gemm<0,0,0><<<gg, 256, 0, stream>>>(z, v_pwc, hb);
  k_dwise<0><<<gd, 256, 0, stream>>>(hb, z, v_dwc, vb, nullptr);
  k_gram<<<dim3(24, 24), 256, 0, stream>>>(qb, kb, Gp);
  k_attn<<<B_, 256, 0, stream>>>(Gp, qqp, kkp, temp, proj, M);
  k_gemm<1,1,1><<<gg, 256, 0, stream>>>(vb, M, out);
}